// Round 6
// baseline (312.166 us; speedup 1.0000x reference)
//
#include <hip/hip_runtime.h>
#include <math.h>

// SuperLoss elementwise (LAM=1, TAU=0):
//   il  = BCE_with_logits(pr, gt) = max(pr,0) - pr*gt + log1p(exp(-|pr|))  (>= 0)
//   y   = il/2;  w = LambertW(y);  out = sigma*il + log(sigma)^2 = w*(w+2)
//   [via w*e^w = y => sigma = e^{-w} = w/y]
//
// Lambert W, exp-free refinement (r1; verified: VALUBusy 45% -> 21-24%):
//   w0 = log1p(y) => e^{w0} = 1+y EXACTLY => Halley step 1 needs no exp.
//   Step 2: e^{w1} = (1+y)*e^{w1-w0}, delta in [-0.6,0] -> 4-term Taylor,
//   then one Newton step. Trans budget/elem: exp + 2 log + 2 rcp = 5.
//
// Measured history:
//   r0 4e/t: 112us | r2 stride2+NT: 130us | r3 8e/t chunk: 112us
//   r4 +NT: 126us (FETCH unchanged -> L3-eviction theory refuted)
//   r5 16e/t batch: 112us, VGPR=28 -> compiler SERIALIZED the batch (8 live
//      dwordx4 results need 32 VGPRs; it kept 28 total). r0/r3/r5 compile to
//      the same effective 2-4-outstanding-load schedule => identical times.
//   Floors: VALU 26us (23% x 112), HBM 268MB @ 6.3TB/s = 43us. Latency-bound
//   with low load duty-cycle, NOT a bandwidth wall.
//
// THIS ROUND: force MLP via structure, not hints. Persistent grid-stride
// (2048 blocks = 8/CU, 32 waves/CU) with register double-buffering through a
// loop-carried dependency: prefetch iter i+1 at loop top, compute iter i from
// last iter's regs. Compiler must emit load(pn,gn) -> vmcnt(2) -> compute ->
// store -> backedge: 2 loads in flight across the whole compute phase
// (counted-vmcnt pattern in plain HIP). Tell: VGPR should rise to ~40-56.

typedef float f32x4 __attribute__((ext_vector_type(4)));

__device__ __forceinline__ float superloss_elem(float pr, float gt) {
    const float LOG2E = 1.44269504f;
    const float LN2   = 0.69314718f;

    // Stable BCE with logits (base-2 hardware trans ops)
    float t  = __builtin_amdgcn_exp2f(-fabsf(pr) * LOG2E);   // e^{-|pr|}
    float lg = __builtin_amdgcn_logf(1.0f + t);              // log2(1+t)
    float il = __fmaf_rn(-pr, gt, fmaxf(pr, 0.0f));
    il = __fmaf_rn(LN2, lg, il);                             // + log1p(e^{-|pr|})

    float y   = 0.5f * il;                                   // y >= 0
    float opy = 1.0f + y;                                    // = e^{w0}, exact
    float w0  = LN2 * __builtin_amdgcn_logf(opy);            // log1p(y)

    // Halley step 1 (exp-free: e^{w0} = opy)
    float f   = __fmaf_rn(w0, opy, -y);
    float wp1 = w0 + 1.0f;
    float num = 2.0f * f * wp1;
    float den = __fmaf_rn(opy + opy, wp1 * wp1, -(w0 + 2.0f) * f);
    float w1  = __fmaf_rn(-num, __builtin_amdgcn_rcpf(den), w0);

    // e^{w1} = opy * e^{nd}, nd = w1 - w0 in [-0.6, 0]; 4th-order Taylor
    float nd = w1 - w0;
    float p  = __fmaf_rn(nd, 0.041666668f, 0.16666667f);
    p = __fmaf_rn(nd, p, 0.5f);
    p = __fmaf_rn(nd, p, 1.0f);
    p = __fmaf_rn(nd, p, 1.0f);
    float e = opy * p;

    // Newton step
    float f2 = __fmaf_rn(w1, e, -y);
    float d2 = e * (w1 + 1.0f);
    float w  = __fmaf_rn(-f2, __builtin_amdgcn_rcpf(d2), w1);

    float u = w + 1.0f;
    return __fmaf_rn(u, u, -1.0f);                           // w*(w+2)
}

__device__ __forceinline__ f32x4 superloss_vec(f32x4 p, f32x4 g) {
    f32x4 o;
    o.x = superloss_elem(p.x, g.x);
    o.y = superloss_elem(p.y, g.y);
    o.z = superloss_elem(p.z, g.z);
    o.w = superloss_elem(p.w, g.w);
    return o;
}

__global__ __launch_bounds__(256) void superloss_pipe(const f32x4* __restrict__ pr,
                                                      const f32x4* __restrict__ gt,
                                                      f32x4* __restrict__ out,
                                                      int n4) {
    const int stride = gridDim.x * blockDim.x;
    int idx = blockIdx.x * blockDim.x + threadIdx.x;
    if (idx >= n4) return;

    // Software pipeline, depth 1: (pc,gc) = current, (pn,gn) = prefetch.
    f32x4 pc = pr[idx];
    f32x4 gc = gt[idx];
    int nidx = idx + stride;
    while (nidx < n4) {
        f32x4 pn = pr[nidx];       // issued before compute; stays in flight
        f32x4 gn = gt[nidx];       // across the whole superloss_vec body
        out[idx] = superloss_vec(pc, gc);
        pc = pn;
        gc = gn;
        idx = nidx;
        nidx += stride;
    }
    out[idx] = superloss_vec(pc, gc);
}

__global__ __launch_bounds__(256) void superloss_scalar(const float* __restrict__ pr,
                                                        const float* __restrict__ gt,
                                                        float* __restrict__ out,
                                                        int base, int n) {
    int i = base + blockIdx.x * blockDim.x + threadIdx.x;
    if (i < n) {
        out[i] = superloss_elem(pr[i], gt[i]);
    }
}

extern "C" void kernel_launch(void* const* d_in, const int* in_sizes, int n_in,
                              void* d_out, int out_size, void* d_ws, size_t ws_size,
                              hipStream_t stream) {
    const float* pr = (const float*)d_in[0];
    const float* gt = (const float*)d_in[1];
    float* out = (float*)d_out;
    int n = in_sizes[0];

    int n4 = n / 4;
    if (n4 > 0) {
        int blocks = (n4 + 255) / 256;
        if (blocks > 2048) blocks = 2048;   // 8 blocks/CU, grid-stride
        superloss_pipe<<<blocks, 256, 0, stream>>>((const f32x4*)pr, (const f32x4*)gt,
                                                   (f32x4*)out, n4);
    }
    int rem = n - n4 * 4;
    if (rem > 0) {
        superloss_scalar<<<1, 256, 0, stream>>>(pr, gt, out, n4 * 4, n);
    }
}